// Round 16
// baseline (174.014 us; speedup 1.0000x reference)
//
#include <hip/hip_runtime.h>
#include <hip/hip_bf16.h>
#include <hip/hip_fp16.h>
#include <hip/hip_cooperative_groups.h>

namespace cg = cooperative_groups;

#define BB 8
#define NN 1024
#define FIN 128
#define FOUT 64
#define HH 4
#define EPSV 1e-7f
#define SLOPE 0.2f
#define LOG2E 1.44269504088896340736f

typedef _Float16 v8h __attribute__((ext_vector_type(8)));
typedef _Float16 v4h __attribute__((ext_vector_type(4)));
typedef _Float16 v2h __attribute__((ext_vector_type(2)));
typedef __fp16 v2hf __attribute__((ext_vector_type(2)));
typedef float v4f __attribute__((ext_vector_type(4)));

union U8 { v2h p[4]; v8h v; };
union U2 { v2hf hf; v2h h; };

__device__ __forceinline__ v2h clamp01(v2h x) {
  v2h zero = {(_Float16)0.0f, (_Float16)0.0f};
  v2h one = {(_Float16)1.0f, (_Float16)1.0f};
  return __builtin_elementwise_min(__builtin_elementwise_max(x, zero), one);
}

__device__ __forceinline__ v2h cvt2(float a, float b) {
  U2 u;
  u.hf = __builtin_amdgcn_cvt_pkrtz(a, b);
  return u.h;
}

__device__ __forceinline__ float dot2(v2h a, v2h b, float c) {
  U2 ua, ub;
  ua.h = a;
  ub.h = b;
  return __builtin_amdgcn_fdot2(ua.hf, ub.hf, c, false);
}

struct SK1 { _Float16 xs[16][136]; };
struct SKB { v2h si_p[2][4][16], di_p[2][4][16], e2i_p[2][4][16]; };
struct SK3 { float rbuf[64]; _Float16 tile[64 * 66]; };
struct SK4 {
  unsigned long long Ab[32][17];
  _Float16 tjl[2][1024], djl[2][1024], e2jl[2][1024];
  _Float16 lut[256][8];
  float sil[2][32], e2il[2][32], dil[2][32];
  float red[2][2][64][33];
};
union Smem { SK1 k1; SKB kb; SK3 k3; SK4 k4; };

// ---------------- MEGA: one cooperative kernel, grid 256 x 512 --------------
// 1 block/CU guaranteed co-resident. Each phase runs 2 sequential reps.
__global__ __launch_bounds__(512, 2) void mega(
    const float* __restrict__ A, const float* __restrict__ x,
    const float* __restrict__ W, const float* __restrict__ aw,
    const float* __restrict__ ab, _Float16* __restrict__ WhH,
    _Float16* __restrict__ VTt, _Float16* __restrict__ Wtt,
    float* __restrict__ si2, float* __restrict__ part,
    unsigned long long* __restrict__ Abits, _Float16* __restrict__ tjh,
    _Float16* __restrict__ djh, _Float16* __restrict__ e2jh,
    float* __restrict__ e2i_t, float* __restrict__ di_t,
    float* __restrict__ out) {
  __shared__ Smem sm;
  cg::grid_group grid = cg::this_grid();
  int bid = blockIdx.x;
  int tid = threadIdx.x;

  // PHASE 0: Wtt (blocks 0..7)
  if (bid < 8) {
#pragma unroll
    for (int it = 0; it < 8; ++it) {
      int idx = bid * 4096 + it * 512 + tid;
      int e = idx & 7, ln = (idx >> 3) & 15, kgg = (idx >> 7) & 15,
          ct = idx >> 11;
      int c = ct * 16 + ln, k = kgg * 8 + e;
      Wtt[idx] = (_Float16)W[(size_t)(c >> 6) * 8192 + k * 64 + (c & 63)];
    }
  }
  grid.sync();

  // PHASE 1: Wh = x@W MFMA + s_i/s_j + exp tables (2 reps of 16-row tiles)
  for (int r = 0; r < 2; ++r) {
    int tile = bid + r * 256;
    if (r) __syncthreads();
    {
      int row = tid >> 5, c4 = (tid & 31) * 4;
      float4 v = *(const float4*)(x + ((size_t)tile * 16 + row) * FIN + c4);
      v4h hv;
      hv[0] = (_Float16)v.x; hv[1] = (_Float16)v.y;
      hv[2] = (_Float16)v.z; hv[3] = (_Float16)v.w;
      *(v4h*)(&sm.k1.xs[row][c4]) = hv;
    }
    __syncthreads();
    if (tid < 256) {
      int w = tid >> 6, l = tid & 63;
      int kg = l >> 4, ln = l & 15;
      v4f acc[4] = {{}, {}, {}, {}};
#pragma unroll
      for (int ks = 0; ks < 4; ++ks) {
        v8h af = *(const v8h*)(&sm.k1.xs[ln][ks * 32 + kg * 8]);
        int kgg = ks * 4 + kg;
#pragma unroll
        for (int t = 0; t < 4; ++t) {
          int ct = w * 4 + t;
          v8h bf =
              *(const v8h*)(Wtt + (((size_t)ct * 16 + kgg) * 16 + ln) * 8);
          acc[t] =
              __builtin_amdgcn_mfma_f32_16x16x32_f16(af, bf, acc[t], 0, 0, 0);
        }
      }
      float a1v[4], a2v[4];
#pragma unroll
      for (int t = 0; t < 4; ++t) {
        a1v[t] = aw[w * 128 + t * 16 + ln];
        a2v[t] = aw[w * 128 + 64 + t * 16 + ln];
      }
      float abv = ab[w];
#pragma unroll
      for (int rr2 = 0; rr2 < 4; ++rr2) {
        float v1 = acc[0][rr2] * a1v[0] + acc[1][rr2] * a1v[1] +
                   acc[2][rr2] * a1v[2] + acc[3][rr2] * a1v[3];
        float v2 = acc[0][rr2] * a2v[0] + acc[1][rr2] * a2v[1] +
                   acc[2][rr2] * a2v[2] + acc[3][rr2] * a2v[3];
#pragma unroll
        for (int off = 1; off < 16; off <<= 1) {
          v1 += __shfl_xor(v1, off);
          v2 += __shfl_xor(v2, off);
        }
        if (ln == 0) {
          int gr = tile * 16 + kg * 4 + rr2;
          int b_ = gr >> 10, n_ = gr & 1023;
          size_t rw = ((size_t)b_ * HH + w) * NN + n_;
          float v1L = v1 * LOG2E;
          float tjL = (v2 + abv) * LOG2E;
          si2[rw] = v1L;
          float e1i = __builtin_amdgcn_exp2f(v1L);
          float e2i = __builtin_amdgcn_exp2f(0.2f * v1L);
          e2i_t[rw] = e2i;
          di_t[rw] = e1i - e2i;
          float e1j = __builtin_amdgcn_exp2f(tjL);
          float e2j = __builtin_amdgcn_exp2f(0.2f * tjL);
          tjh[rw] = (_Float16)tjL;
          e2jh[rw] = (_Float16)e2j;
          djh[rw] = (_Float16)(e1j - e2j);
        }
      }
#pragma unroll
      for (int t = 0; t < 4; ++t) {
#pragma unroll
        for (int rr2 = 0; rr2 < 4; ++rr2) {
          int gr = tile * 16 + kg * 4 + rr2;
          int b_ = gr >> 10, n_ = gr & 1023;
          WhH[(((size_t)b_ * HH + w) * NN + n_) * 64 + (t * 16 + ln)] =
              (_Float16)acc[t][rr2];
        }
      }
    }
  }
  grid.sync();

  // PHASE 2: colsum (packed interp) + A bit-pack (2 reps; b differs by 4)
  for (int r = 0; r < 2; ++r) {
    int unit = tid >> 8, lt = tid & 255;
    int u = r * 512 + bid * 2 + unit;
    int jt = u & 3, is = (u >> 2) & 31, b = u >> 7;
    int w = lt >> 6, lane = lt & 63;
    int j = jt * 256 + lt;
    int i0 = is * 32;
    if (r) __syncthreads();
    if (lt < 64) {
      int h = lt >> 4, pp = lt & 15;
      size_t row = ((size_t)(b * HH + h)) * NN + i0 + 2 * pp;
      sm.kb.si_p[unit][h][pp] = cvt2(si2[row], si2[row + 1]);
      sm.kb.di_p[unit][h][pp] = cvt2(di_t[row], di_t[row + 1]);
      sm.kb.e2i_p[unit][h][pp] = cvt2(e2i_t[row], e2i_t[row + 1]);
    }
    __syncthreads();
    v2h tjb[4], djb[4], ejb[4];
#pragma unroll
    for (int h = 0; h < 4; ++h) {
      size_t jr = ((size_t)(b * HH + h)) * NN + j;
      _Float16 t = tjh[jr], d = djh[jr], e = e2jh[jr];
      tjb[h][0] = t; tjb[h][1] = t;
      djb[h][0] = d; djb[h][1] = d;
      ejb[h][0] = e; ejb[h][1] = e;
    }
    v2h big = {(_Float16)4096.0f, (_Float16)4096.0f};
    float acc[4] = {0.f, 0.f, 0.f, 0.f};
    const float* Ap = A + ((size_t)b * NN + i0) * NN + j;
    unsigned long long myword = 0ull;
#pragma unroll
    for (int c = 0; c < 4; ++c) {
      float av[8];
#pragma unroll
      for (int q = 0; q < 8; ++q) av[q] = Ap[(size_t)(c * 8 + q) * NN];
      v2h apk[4];
#pragma unroll
      for (int q = 0; q < 4; ++q) apk[q] = cvt2(av[2 * q], av[2 * q + 1]);
#pragma unroll
      for (int q = 0; q < 8; ++q) {
        unsigned long long m = __ballot(av[q] != 0.0f);
        if (lane == c * 8 + q) myword = m;
      }
#pragma unroll
      for (int h = 0; h < 4; ++h) {
        U8 si4, di4, ei4;
        si4.v = *(const v8h*)&sm.kb.si_p[unit][h][c * 4];
        di4.v = *(const v8h*)&sm.kb.di_p[unit][h][c * 4];
        ei4.v = *(const v8h*)&sm.kb.e2i_p[unit][h][c * 4];
#pragma unroll
        for (int pp = 0; pp < 4; ++pp) {
          v2h f = si4.p[pp] + tjb[h];
          v2h s = clamp01(f * big);
          v2h ei = s * di4.p[pp] + ei4.p[pp];
          v2h ej = s * djb[h] + ejb[h];
          v2h p = ei * ej;
          acc[h] = dot2(p, apk[pp], acc[h]);
        }
      }
    }
    if (lane < 32)
      Abits[((size_t)b * NN + i0 + lane) * 16 + jt * 4 + w] = myword;
#pragma unroll
    for (int h = 0; h < 4; ++h)
      part[((size_t)(is * 32) + b * HH + h) * NN + j] = acc[h];
  }
  grid.sync();

  // PHASE 3: r[j]; VTt = (f16) r*Wh tiled (2 reps)
  for (int r = 0; r < 2; ++r) {
    int bid9 = bid + r * 256;
    int b = bid9 & 7, rest = bid9 >> 3;
    int h = rest & 3, jt = rest >> 2;
    int bh = b * HH + h, j0 = jt * 64;
    if (r) __syncthreads();
    if (tid < 64) {
      float s = 0.f;
#pragma unroll
      for (int is = 0; is < 32; ++is)
        s += part[((size_t)(is * 32) + bh) * NN + j0 + tid];
      sm.k3.rbuf[tid] = 1.0f / (s + EPSV);
    }
    __syncthreads();
#pragma unroll
    for (int it = 0; it < 8; ++it) {
      int lin = it * 512 + tid;
      int jj = lin >> 6, o = lin & 63;
      float v =
          (float)WhH[((size_t)bh * NN + j0 + jj) * 64 + o] * sm.k3.rbuf[jj];
      sm.k3.tile[o * 66 + jj] = (_Float16)v;
    }
    __syncthreads();
#pragma unroll
    for (int it = 0; it < 8; ++it) {
      int lin = it * 512 + tid;
      int o = lin >> 6, jj64 = lin & 63;
      int j = j0 + jj64;
      int jb = j >> 5, jj = j & 31;
      VTt[(((size_t)bh * 32 + jb) * 64 + o) * 32 + jj] =
          sm.k3.tile[o * 66 + jj64];
    }
  }
  grid.sync();

  // PHASE 4: out = P @ V' via MFMA (2 reps over i-tiles; b,hp invariant)
  {
    int b = bid & 7, hp = (bid >> 3) & 1;
    {
      size_t base = (size_t)(b * HH + hp * 2) * NN;
      const unsigned int* s1 = (const unsigned int*)(tjh + base);
      const unsigned int* s2 = (const unsigned int*)(djh + base);
      const unsigned int* s3 = (const unsigned int*)(e2jh + base);
      unsigned int* d1 = (unsigned int*)&sm.k4.tjl[0][0];
      unsigned int* d2 = (unsigned int*)&sm.k4.djl[0][0];
      unsigned int* d3 = (unsigned int*)&sm.k4.e2jl[0][0];
      d1[tid] = s1[tid]; d1[tid + 512] = s1[tid + 512];
      d2[tid] = s2[tid]; d2[tid + 512] = s2[tid + 512];
      d3[tid] = s3[tid]; d3[tid + 512] = s3[tid + 512];
    }
    if (tid < 256) {
#pragma unroll
      for (int e = 0; e < 8; ++e)
        sm.k4.lut[tid][e] = ((tid >> e) & 1) ? (_Float16)1.0f : (_Float16)0.0f;
    }
    for (int r = 0; r < 2; ++r) {
      int it = (bid >> 4) + r * 16;
      int i0 = it * 32;
      if (tid < 64) {
        int hh = tid >> 5, ii = tid & 31;
        size_t row = (size_t)(b * HH + hp * 2 + hh) * NN + i0 + ii;
        sm.k4.sil[hh][ii] = si2[row];
        sm.k4.e2il[hh][ii] = e2i_t[row];
        sm.k4.dil[hh][ii] = di_t[row];
      }
      {
        int row = tid >> 4, word = tid & 15;
        sm.k4.Ab[row][word] = Abits[((size_t)b * NN + i0 + row) * 16 + word];
      }
      __syncthreads();

      int w = tid >> 6, l = tid & 63;
      int hh = w & 1, jq4 = w >> 1;
      int kg = l >> 4, ln = l & 15;
      _Float16 sih0 = (_Float16)sm.k4.sil[hh][ln];
      _Float16 sih1 = (_Float16)sm.k4.sil[hh][16 + ln];
      v2h si0 = {sih0, sih0}, si1 = {sih1, sih1};
      _Float16 e2h0 = (_Float16)sm.k4.e2il[hh][ln],
               e2h1 = (_Float16)sm.k4.e2il[hh][16 + ln];
      _Float16 dih0 = (_Float16)sm.k4.dil[hh][ln],
               dih1 = (_Float16)sm.k4.dil[hh][16 + ln];
      v2h e2i0 = {e2h0, e2h0}, e2i1 = {e2h1, e2h1};
      v2h di0 = {dih0, dih0}, di1 = {dih1, dih1};
      v2h big = {(_Float16)4096.0f, (_Float16)4096.0f};
      int bh = b * HH + hp * 2 + hh;
      v4f acc0[4] = {{}, {}, {}, {}};
      v4f acc1[4] = {{}, {}, {}, {}};
      const _Float16* VTb = VTt + (size_t)bh * 32 * 64 * 32;
      int jbase = jq4 * 256;

#pragma unroll 2
      for (int jq = 0; jq < 8; ++jq) {
        int j = jbase + jq * 32 + kg * 8;
        int widx = j >> 6, sh = j & 63;
        unsigned int bits0 = (unsigned int)(sm.k4.Ab[ln][widx] >> sh) & 0xffu;
        unsigned int bits1 =
            (unsigned int)(sm.k4.Ab[16 + ln][widx] >> sh) & 0xffu;
        U8 tj8, dj8, ej8, m0, m1, af0, af1;
        tj8.v = *(const v8h*)&sm.k4.tjl[hh][j];
        dj8.v = *(const v8h*)&sm.k4.djl[hh][j];
        ej8.v = *(const v8h*)&sm.k4.e2jl[hh][j];
        m0.v = *(const v8h*)&sm.k4.lut[bits0][0];
        m1.v = *(const v8h*)&sm.k4.lut[bits1][0];
#pragma unroll
        for (int q = 0; q < 4; ++q) {
          v2h f0 = tj8.p[q] + si0;
          v2h s0 = clamp01(f0 * big);
          v2h ej0 = s0 * dj8.p[q] + ej8.p[q];
          v2h ei0 = s0 * di0 + e2i0;
          af0.p[q] = ei0 * ej0 * m0.p[q];
          v2h f1 = tj8.p[q] + si1;
          v2h s1v = clamp01(f1 * big);
          v2h ej1 = s1v * dj8.p[q] + ej8.p[q];
          v2h ei1 = s1v * di1 + e2i1;
          af1.p[q] = ei1 * ej1 * m1.p[q];
        }
        const _Float16* vb = VTb + (size_t)(j >> 5) * 2048 + kg * 8;
        v8h b0 = *(const v8h*)(vb + (0 * 16 + ln) * 32);
        v8h b1 = *(const v8h*)(vb + (1 * 16 + ln) * 32);
        v8h b2 = *(const v8h*)(vb + (2 * 16 + ln) * 32);
        v8h b3 = *(const v8h*)(vb + (3 * 16 + ln) * 32);
        acc0[0] = __builtin_amdgcn_mfma_f32_16x16x32_f16(af0.v, b0, acc0[0],
                                                         0, 0, 0);
        acc1[0] = __builtin_amdgcn_mfma_f32_16x16x32_f16(af1.v, b0, acc1[0],
                                                         0, 0, 0);
        acc0[1] = __builtin_amdgcn_mfma_f32_16x16x32_f16(af0.v, b1, acc0[1],
                                                         0, 0, 0);
        acc1[1] = __builtin_amdgcn_mfma_f32_16x16x32_f16(af1.v, b1, acc1[1],
                                                         0, 0, 0);
        acc0[2] = __builtin_amdgcn_mfma_f32_16x16x32_f16(af0.v, b2, acc0[2],
                                                         0, 0, 0);
        acc1[2] = __builtin_amdgcn_mfma_f32_16x16x32_f16(af1.v, b2, acc1[2],
                                                         0, 0, 0);
        acc0[3] = __builtin_amdgcn_mfma_f32_16x16x32_f16(af0.v, b3, acc0[3],
                                                         0, 0, 0);
        acc1[3] = __builtin_amdgcn_mfma_f32_16x16x32_f16(af1.v, b3, acc1[3],
                                                         0, 0, 0);
      }

      if (jq4 == 1 || jq4 == 3) {
        int slot = jq4 >> 1;
#pragma unroll
        for (int t = 0; t < 4; ++t)
#pragma unroll
          for (int rr2 = 0; rr2 < 4; ++rr2) {
            sm.k4.red[hh][slot][l][t * 4 + rr2] = acc0[t][rr2];
            sm.k4.red[hh][slot][l][16 + t * 4 + rr2] = acc1[t][rr2];
          }
      }
      __syncthreads();
      if (jq4 == 0 || jq4 == 2) {
        int slot = jq4 >> 1;
#pragma unroll
        for (int t = 0; t < 4; ++t)
#pragma unroll
          for (int rr2 = 0; rr2 < 4; ++rr2) {
            acc0[t][rr2] += sm.k4.red[hh][slot][l][t * 4 + rr2];
            acc1[t][rr2] += sm.k4.red[hh][slot][l][16 + t * 4 + rr2];
          }
      }
      __syncthreads();
      if (jq4 == 2) {
#pragma unroll
        for (int t = 0; t < 4; ++t)
#pragma unroll
          for (int rr2 = 0; rr2 < 4; ++rr2) {
            sm.k4.red[hh][0][l][t * 4 + rr2] = acc0[t][rr2];
            sm.k4.red[hh][0][l][16 + t * 4 + rr2] = acc1[t][rr2];
          }
      }
      __syncthreads();
      if (jq4 == 0) {
#pragma unroll
        for (int t = 0; t < 4; ++t)
#pragma unroll
          for (int rr2 = 0; rr2 < 4; ++rr2) {
            acc0[t][rr2] += sm.k4.red[hh][0][l][t * 4 + rr2];
            acc1[t][rr2] += sm.k4.red[hh][0][l][16 + t * 4 + rr2];
          }
#pragma unroll
        for (int rr2 = 0; rr2 < 4; ++rr2) {
          int gi0 = i0 + kg * 4 + rr2;
          float* op0 = out + ((size_t)b * NN + gi0) * 256 + (hp * 2 + hh) * 64;
          op0[0 * 16 + ln] = acc0[0][rr2];
          op0[1 * 16 + ln] = acc0[1][rr2];
          op0[2 * 16 + ln] = acc0[2][rr2];
          op0[3 * 16 + ln] = acc0[3][rr2];
          float* op1 = op0 + 16 * 256;
          op1[0 * 16 + ln] = acc1[0][rr2];
          op1[1 * 16 + ln] = acc1[1][rr2];
          op1[2 * 16 + ln] = acc1[2][rr2];
          op1[3 * 16 + ln] = acc1[3][rr2];
        }
      }
      __syncthreads();
    }
  }
}

// =================== FALLBACK: R14 5-kernel pipeline (known-good) ===========
__global__ __launch_bounds__(256) void k0_wt(const float* __restrict__ W,
                                             _Float16* __restrict__ Wtt) {
  for (int it = 0; it < 16; ++it) {
    int idx = blockIdx.x * 4096 + it * 256 + threadIdx.x;
    int e = idx & 7, ln = (idx >> 3) & 15, kgg = (idx >> 7) & 15,
        ct = idx >> 11;
    int c = ct * 16 + ln, k = kgg * 8 + e;
    Wtt[idx] = (_Float16)W[(size_t)(c >> 6) * 8192 + k * 64 + (c & 63)];
  }
}

__global__ __launch_bounds__(256) void k1_whm(
    const float* __restrict__ x, const _Float16* __restrict__ Wtt,
    const float* __restrict__ aw, const float* __restrict__ ab,
    _Float16* __restrict__ WhH, float* __restrict__ si2,
    _Float16* __restrict__ tjh, _Float16* __restrict__ djh,
    _Float16* __restrict__ e2jh, float* __restrict__ e2i_t,
    float* __restrict__ di_t) {
  __shared__ _Float16 xs[16][136];
  int tid = threadIdx.x;
#pragma unroll
  for (int t2 = 0; t2 < 2; ++t2) {
    int idx = t2 * 256 + tid;
    int row = idx >> 5, c4 = (idx & 31) * 4;
    float4 v = *(const float4*)(x + ((size_t)blockIdx.x * 16 + row) * FIN + c4);
    v4h hv;
    hv[0] = (_Float16)v.x; hv[1] = (_Float16)v.y;
    hv[2] = (_Float16)v.z; hv[3] = (_Float16)v.w;
    *(v4h*)(&xs[row][c4]) = hv;
  }
  __syncthreads();
  int w = tid >> 6, l = tid & 63;
  int kg = l >> 4, ln = l & 15;
  v4f acc[4] = {{}, {}, {}, {}};
#pragma unroll
  for (int ks = 0; ks < 4; ++ks) {
    v8h af = *(const v8h*)(&xs[ln][ks * 32 + kg * 8]);
    int kgg = ks * 4 + kg;
#pragma unroll
    for (int t = 0; t < 4; ++t) {
      int ct = w * 4 + t;
      v8h bf = *(const v8h*)(Wtt + (((size_t)ct * 16 + kgg) * 16 + ln) * 8);
      acc[t] = __builtin_amdgcn_mfma_f32_16x16x32_f16(af, bf, acc[t], 0, 0, 0);
    }
  }
  float a1v[4], a2v[4];
#pragma unroll
  for (int t = 0; t < 4; ++t) {
    a1v[t] = aw[w * 128 + t * 16 + ln];
    a2v[t] = aw[w * 128 + 64 + t * 16 + ln];
  }
  float abv = ab[w];
#pragma unroll
  for (int r = 0; r < 4; ++r) {
    float v1 = acc[0][r] * a1v[0] + acc[1][r] * a1v[1] +
               acc[2][r] * a1v[2] + acc[3][r] * a1v[3];
    float v2 = acc[0][r] * a2v[0] + acc[1][r] * a2v[1] +
               acc[2][r] * a2v[2] + acc[3][r] * a2v[3];
#pragma unroll
    for (int off = 1; off < 16; off <<= 1) {
      v1 += __shfl_xor(v1, off);
      v2 += __shfl_xor(v2, off);
    }
    if (ln == 0) {
      int gr = blockIdx.x * 16 + kg * 4 + r;
      int b_ = gr >> 10, n_ = gr & 1023;
      size_t row = ((size_t)b_ * HH + w) * NN + n_;
      float v1L = v1 * LOG2E;
      float tjL = (v2 + abv) * LOG2E;
      si2[row] = v1L;
      float e1i = __builtin_amdgcn_exp2f(v1L);
      float e2i = __builtin_amdgcn_exp2f(0.2f * v1L);
      e2i_t[row] = e2i;
      di_t[row] = e1i - e2i;
      float e1j = __builtin_amdgcn_exp2f(tjL);
      float e2j = __builtin_amdgcn_exp2f(0.2f * tjL);
      tjh[row] = (_Float16)tjL;
      e2jh[row] = (_Float16)e2j;
      djh[row] = (_Float16)(e1j - e2j);
    }
  }
#pragma unroll
  for (int t = 0; t < 4; ++t) {
#pragma unroll
    for (int r = 0; r < 4; ++r) {
      int gr = blockIdx.x * 16 + kg * 4 + r;
      int b_ = gr >> 10, n_ = gr & 1023;
      WhH[(((size_t)b_ * HH + w) * NN + n_) * 64 + (t * 16 + ln)] =
          (_Float16)acc[t][r];
    }
  }
}

__global__ __launch_bounds__(256) void kb_colsum_bits(
    const float* __restrict__ A, const float* __restrict__ si2,
    const float* __restrict__ e2i_t, const float* __restrict__ di_t,
    const _Float16* __restrict__ tjh, const _Float16* __restrict__ djh,
    const _Float16* __restrict__ e2jh, float* __restrict__ part,
    unsigned long long* __restrict__ Abits) {
  __shared__ v2h si_p[4][16], di_p[4][16], e2i_p[4][16];
  int b = blockIdx.z, is = blockIdx.y, jt = blockIdx.x;
  int tid = threadIdx.x;
  int w = tid >> 6, lane = tid & 63;
  int j = jt * 256 + tid;
  int i0 = is * 32;
  if (tid < 64) {
    int h = tid >> 4, pp = tid & 15;
    size_t row = ((size_t)(b * HH + h)) * NN + i0 + 2 * pp;
    si_p[h][pp] = cvt2(si2[row], si2[row + 1]);
    di_p[h][pp] = cvt2(di_t[row], di_t[row + 1]);
    e2i_p[h][pp] = cvt2(e2i_t[row], e2i_t[row + 1]);
  }
  __syncthreads();
  v2h tjb[4], djb[4], ejb[4];
#pragma unroll
  for (int h = 0; h < 4; ++h) {
    size_t jr = ((size_t)(b * HH + h)) * NN + j;
    _Float16 t = tjh[jr], d = djh[jr], e = e2jh[jr];
    tjb[h][0] = t; tjb[h][1] = t;
    djb[h][0] = d; djb[h][1] = d;
    ejb[h][0] = e; ejb[h][1] = e;
  }
  v2h big = {(_Float16)4096.0f, (_Float16)4096.0f};
  float acc[4] = {0.f, 0.f, 0.f, 0.f};
  const float* Ap = A + ((size_t)b * NN + i0) * NN + j;
  unsigned long long myword = 0ull;
#pragma unroll
  for (int c = 0; c < 4; ++c) {
    float av[8];
#pragma unroll
    for (int q = 0; q < 8; ++q) av[q] = Ap[(size_t)(c * 8 + q) * NN];
    v2h apk[4];
#pragma unroll
    for (int q = 0; q < 4; ++q) apk[q] = cvt2(av[2 * q], av[2 * q + 1]);
#pragma unroll
    for (int q = 0; q < 8; ++q) {
      unsigned long long m = __ballot(av[q] != 0.0f);
      if (lane == c * 8 + q) myword = m;
    }
#pragma unroll
    for (int h = 0; h < 4; ++h) {
      U8 si4, di4, ei4;
      si4.v = *(const v8h*)&si_p[h][c * 4];
      di4.v = *(const v8h*)&di_p[h][c * 4];
      ei4.v = *(const v8h*)&e2i_p[h][c * 4];
#pragma unroll
      for (int pp = 0; pp < 4; ++pp) {
        v2h f = si4.p[pp] + tjb[h];
        v2h s = clamp01(f * big);
        v2h ei = s * di4.p[pp] + ei4.p[pp];
        v2h ej = s * djb[h] + ejb[h];
        v2h p = ei * ej;
        acc[h] = dot2(p, apk[pp], acc[h]);
      }
    }
  }
  if (lane < 32)
    Abits[((size_t)b * NN + i0 + lane) * 16 + jt * 4 + w] = myword;
#pragma unroll
  for (int h = 0; h < 4; ++h)
    part[((size_t)(is * 32) + b * HH + h) * NN + j] = acc[h];
}

__global__ __launch_bounds__(256) void k3_scale_tr(
    const _Float16* __restrict__ WhH, const float* __restrict__ part,
    _Float16* __restrict__ VTt) {
  __shared__ float rbuf[64];
  __shared__ _Float16 tile[64 * 66];
  int bid = blockIdx.x;
  int b = bid & 7, rest = bid >> 3;
  int h = rest & 3, jt = rest >> 2;
  int bh = b * HH + h, j0 = jt * 64;
  int tid = threadIdx.x;
  if (tid < 64) {
    float s = 0.f;
#pragma unroll
    for (int is = 0; is < 32; ++is)
      s += part[((size_t)(is * 32) + bh) * NN + j0 + tid];
    rbuf[tid] = 1.0f / (s + EPSV);
  }
  __syncthreads();
#pragma unroll
  for (int it = 0; it < 16; ++it) {
    int lin = it * 256 + tid;
    int jj = lin >> 6, o = lin & 63;
    float v = (float)WhH[((size_t)bh * NN + j0 + jj) * 64 + o] * rbuf[jj];
    tile[o * 66 + jj] = (_Float16)v;
  }
  __syncthreads();
#pragma unroll
  for (int it = 0; it < 16; ++it) {
    int lin = it * 256 + tid;
    int o = lin >> 6, jj64 = lin & 63;
    int j = j0 + jj64;
    int jb = j >> 5, jj = j & 31;
    VTt[(((size_t)bh * 32 + jb) * 64 + o) * 32 + jj] = tile[o * 66 + jj64];
  }
}

__global__ __launch_bounds__(512, 4) void k4_pv(
    const unsigned long long* __restrict__ Abits,
    const float* __restrict__ si2, const _Float16* __restrict__ tjh,
    const _Float16* __restrict__ djh, const _Float16* __restrict__ e2jh,
    const float* __restrict__ e2i_t, const float* __restrict__ di_t,
    const _Float16* __restrict__ VTt, float* __restrict__ out) {
  __shared__ unsigned long long Ab[32][17];
  __shared__ _Float16 tjl[2][1024];
  __shared__ _Float16 djl[2][1024];
  __shared__ _Float16 e2jl[2][1024];
  __shared__ _Float16 lut[256][8];
  __shared__ float sil[2][32], e2il[2][32], dil[2][32];
  __shared__ float red[2][2][64][33];
  int bid = blockIdx.x;
  int b = bid & 7, hp = (bid >> 3) & 1, it = bid >> 4;
  int i0 = it * 32;
  int tid = threadIdx.x;
  {
    size_t base = (size_t)(b * HH + hp * 2) * NN;
    const unsigned int* s1 = (const unsigned int*)(tjh + base);
    const unsigned int* s2 = (const unsigned int*)(djh + base);
    const unsigned int* s3 = (const unsigned int*)(e2jh + base);
    unsigned int* d1 = (unsigned int*)&tjl[0][0];
    unsigned int* d2 = (unsigned int*)&djl[0][0];
    unsigned int* d3 = (unsigned int*)&e2jl[0][0];
    d1[tid] = s1[tid]; d1[tid + 512] = s1[tid + 512];
    d2[tid] = s2[tid]; d2[tid + 512] = s2[tid + 512];
    d3[tid] = s3[tid]; d3[tid + 512] = s3[tid + 512];
  }
  if (tid < 64) {
    int hh = tid >> 5, ii = tid & 31;
    size_t row = (size_t)(b * HH + hp * 2 + hh) * NN + i0 + ii;
    sil[hh][ii] = si2[row];
    e2il[hh][ii] = e2i_t[row];
    dil[hh][ii] = di_t[row];
  }
  if (tid < 256) {
#pragma unroll
    for (int e = 0; e < 8; ++e)
      lut[tid][e] = ((tid >> e) & 1) ? (_Float16)1.0f : (_Float16)0.0f;
  }
  {
    int row = tid >> 4, word = tid & 15;
    Ab[row][word] = Abits[((size_t)b * NN + i0 + row) * 16 + word];
  }
  __syncthreads();

  int w = tid >> 6, l = tid & 63;
  int hh = w & 1, jq4 = w >> 1;
  int kg = l >> 4, ln = l & 15;
  _Float16 sih0 = (_Float16)sil[hh][ln];
  _Float16 sih1 = (_Float16)sil[hh][16 + ln];
  v2h si0 = {sih0, sih0}, si1 = {sih1, sih1};
  _Float16 e2h0 = (_Float16)e2il[hh][ln], e2h1 = (_Float16)e2il[hh][16 + ln];
  _Float16 dih0 = (_Float16)dil[hh][ln], dih1 = (_Float16)dil[hh][16 + ln];
  v2h e2i0 = {e2h0, e2h0}, e2i1 = {e2h1, e2h1};
  v2h di0 = {dih0, dih0}, di1 = {dih1, dih1};
  v2h big = {(_Float16)4096.0f, (_Float16)4096.0f};
  int bh = b * HH + hp * 2 + hh;
  v4f acc0[4] = {{}, {}, {}, {}};
  v4f acc1[4] = {{}, {}, {}, {}};
  const _Float16* VTb = VTt + (size_t)bh * 32 * 64 * 32;
  int jbase = jq4 * 256;

#pragma unroll 2
  for (int jq = 0; jq < 8; ++jq) {
    int j = jbase + jq * 32 + kg * 8;
    int widx = j >> 6, sh = j & 63;
    unsigned int bits0 = (unsigned int)(Ab[ln][widx] >> sh) & 0xffu;
    unsigned int bits1 = (unsigned int)(Ab[16 + ln][widx] >> sh) & 0xffu;
    U8 tj8, dj8, ej8, m0, m1, af0, af1;
    tj8.v = *(const v8h*)&tjl[hh][j];
    dj8.v = *(const v8h*)&djl[hh][j];
    ej8.v = *(const v8h*)&e2jl[hh][j];
    m0.v = *(const v8h*)&lut[bits0][0];
    m1.v = *(const v8h*)&lut[bits1][0];
#pragma unroll
    for (int q = 0; q < 4; ++q) {
      v2h f0 = tj8.p[q] + si0;
      v2h s0 = clamp01(f0 * big);
      v2h ej0 = s0 * dj8.p[q] + ej8.p[q];
      v2h ei0 = s0 * di0 + e2i0;
      af0.p[q] = ei0 * ej0 * m0.p[q];
      v2h f1 = tj8.p[q] + si1;
      v2h s1v = clamp01(f1 * big);
      v2h ej1 = s1v * dj8.p[q] + ej8.p[q];
      v2h ei1 = s1v * di1 + e2i1;
      af1.p[q] = ei1 * ej1 * m1.p[q];
    }
    const _Float16* vb = VTb + (size_t)(j >> 5) * 2048 + kg * 8;
    v8h b0 = *(const v8h*)(vb + (0 * 16 + ln) * 32);
    v8h b1 = *(const v8h*)(vb + (1 * 16 + ln) * 32);
    v8h b2 = *(const v8h*)(vb + (2 * 16 + ln) * 32);
    v8h b3 = *(const v8h*)(vb + (3 * 16 + ln) * 32);
    acc0[0] = __builtin_amdgcn_mfma_f32_16x16x32_f16(af0.v, b0, acc0[0], 0, 0, 0);
    acc1[0] = __builtin_amdgcn_mfma_f32_16x16x32_f16(af1.v, b0, acc1[0], 0, 0, 0);
    acc0[1] = __builtin_amdgcn_mfma_f32_16x16x32_f16(af0.v, b1, acc0[1], 0, 0, 0);
    acc1[1] = __builtin_amdgcn_mfma_f32_16x16x32_f16(af1.v, b1, acc1[1], 0, 0, 0);
    acc0[2] = __builtin_amdgcn_mfma_f32_16x16x32_f16(af0.v, b2, acc0[2], 0, 0, 0);
    acc1[2] = __builtin_amdgcn_mfma_f32_16x16x32_f16(af1.v, b2, acc1[2], 0, 0, 0);
    acc0[3] = __builtin_amdgcn_mfma_f32_16x16x32_f16(af0.v, b3, acc0[3], 0, 0, 0);
    acc1[3] = __builtin_amdgcn_mfma_f32_16x16x32_f16(af1.v, b3, acc1[3], 0, 0, 0);
  }

  if (jq4 == 1 || jq4 == 3) {
    int slot = jq4 >> 1;
#pragma unroll
    for (int t = 0; t < 4; ++t)
#pragma unroll
      for (int r = 0; r < 4; ++r) {
        red[hh][slot][l][t * 4 + r] = acc0[t][r];
        red[hh][slot][l][16 + t * 4 + r] = acc1[t][r];
      }
  }
  __syncthreads();
  if (jq4 == 0 || jq4 == 2) {
    int slot = jq4 >> 1;
#pragma unroll
    for (int t = 0; t < 4; ++t)
#pragma unroll
      for (int r = 0; r < 4; ++r) {
        acc0[t][r] += red[hh][slot][l][t * 4 + r];
        acc1[t][r] += red[hh][slot][l][16 + t * 4 + r];
      }
  }
  __syncthreads();
  if (jq4 == 2) {
#pragma unroll
    for (int t = 0; t < 4; ++t)
#pragma unroll
      for (int r = 0; r < 4; ++r) {
        red[hh][0][l][t * 4 + r] = acc0[t][r];
        red[hh][0][l][16 + t * 4 + r] = acc1[t][r];
      }
  }
  __syncthreads();
  if (jq4 == 0) {
#pragma unroll
    for (int t = 0; t < 4; ++t)
#pragma unroll
      for (int r = 0; r < 4; ++r) {
        acc0[t][r] += red[hh][0][l][t * 4 + r];
        acc1[t][r] += red[hh][0][l][16 + t * 4 + r];
      }
#pragma unroll
    for (int r = 0; r < 4; ++r) {
      int gi0 = i0 + kg * 4 + r;
      float* op0 = out + ((size_t)b * NN + gi0) * 256 + (hp * 2 + hh) * 64;
      op0[0 * 16 + ln] = acc0[0][r];
      op0[1 * 16 + ln] = acc0[1][r];
      op0[2 * 16 + ln] = acc0[2][r];
      op0[3 * 16 + ln] = acc0[3][r];
      float* op1 = op0 + 16 * 256;
      op1[0 * 16 + ln] = acc1[0][r];
      op1[1 * 16 + ln] = acc1[1][r];
      op1[2 * 16 + ln] = acc1[2][r];
      op1[3 * 16 + ln] = acc1[3][r];
    }
  }
}

extern "C" void kernel_launch(void* const* d_in, const int* in_sizes, int n_in,
                              void* d_out, int out_size, void* d_ws,
                              size_t ws_size, hipStream_t stream) {
  const float* A = (const float*)d_in[0];
  const float* x = (const float*)d_in[1];
  const float* W = (const float*)d_in[2];
  const float* aw = (const float*)d_in[3];
  const float* ab = (const float*)d_in[4];
  float* out = (float*)d_out;
  char* ws = (char*)d_ws;
  _Float16* WhH = (_Float16*)ws;                        // 4 MB
  _Float16* VTt = (_Float16*)(ws + (4u << 20));         // 4 MB
  _Float16* Wtt = (_Float16*)(ws + (8u << 20));         // 64 KB
  float* si2 = (float*)(ws + (8u << 20) + (256u << 10));    // 128 KB
  float* part = (float*)(ws + (8u << 20) + (512u << 10));   // 4 MB
  unsigned long long* Abits =
      (unsigned long long*)(ws + (12u << 20) + (512u << 10));  // 1 MB
  char* tb = ws + (13u << 20) + (512u << 10);
  _Float16* tjh = (_Float16*)tb;                   // 64 KB (B,H,N) f16
  _Float16* djh = (_Float16*)(tb + (64u << 10));   // 64 KB
  _Float16* e2jh = (_Float16*)(tb + (128u << 10)); // 64 KB
  float* e2i_t = (float*)(tb + (192u << 10));      // 128 KB
  float* di_t = (float*)(tb + (320u << 10));       // 128 KB

  void* args[] = {(void*)&A,     (void*)&x,    (void*)&W,     (void*)&aw,
                  (void*)&ab,    (void*)&WhH,  (void*)&VTt,   (void*)&Wtt,
                  (void*)&si2,   (void*)&part, (void*)&Abits, (void*)&tjh,
                  (void*)&djh,   (void*)&e2jh, (void*)&e2i_t, (void*)&di_t,
                  (void*)&out};
  hipError_t err = hipLaunchCooperativeKernel((void*)mega, dim3(256),
                                              dim3(512), args, 0, stream);
  if (err != hipSuccess) {
    // Deterministic fallback: known-good R14 5-kernel pipeline.
    hipLaunchKernelGGL(k0_wt, dim3(8), dim3(256), 0, stream, W, Wtt);
    hipLaunchKernelGGL(k1_whm, dim3(512), dim3(256), 0, stream, x, Wtt, aw,
                       ab, WhH, si2, tjh, djh, e2jh, e2i_t, di_t);
    hipLaunchKernelGGL(kb_colsum_bits, dim3(4, 32, BB), dim3(256), 0, stream,
                       A, si2, e2i_t, di_t, tjh, djh, e2jh, part, Abits);
    hipLaunchKernelGGL(k3_scale_tr, dim3(512), dim3(256), 0, stream, WhH,
                       part, VTt);
    hipLaunchKernelGGL(k4_pv, dim3(512), dim3(512), 0, stream, Abits, si2,
                       tjh, djh, e2jh, e2i_t, di_t, VTt, out);
  }
}

// Round 17
// 44.727 us; speedup vs baseline: 3.8906x; 3.8906x over previous
//
#include <hip/hip_runtime.h>
#include <hip/hip_bf16.h>
#include <hip/hip_fp16.h>

#define BB 8
#define NN 1024
#define FIN 128
#define FOUT 64
#define HH 4
#define EPSV 1e-7f
#define SLOPE 0.2f
#define LOG2E 1.44269504088896340736f

typedef _Float16 v8h __attribute__((ext_vector_type(8)));
typedef _Float16 v4h __attribute__((ext_vector_type(4)));
typedef _Float16 v2h __attribute__((ext_vector_type(2)));
typedef __fp16 v2hf __attribute__((ext_vector_type(2)));
typedef float v4f __attribute__((ext_vector_type(4)));

union U8 { v2h p[4]; v8h v; };
union U2 { v2hf hf; v2h h; };

__device__ __forceinline__ v2h clamp01(v2h x) {
  v2h zero = {(_Float16)0.0f, (_Float16)0.0f};
  v2h one = {(_Float16)1.0f, (_Float16)1.0f};
  return __builtin_elementwise_min(__builtin_elementwise_max(x, zero), one);
}

__device__ __forceinline__ v2h cvt2(float a, float b) {
  U2 u;
  u.hf = __builtin_amdgcn_cvt_pkrtz(a, b);
  return u.h;
}

__device__ __forceinline__ float dot2(v2h a, v2h b, float c) {
  U2 ua, ub;
  ua.h = a;
  ub.h = b;
  return __builtin_amdgcn_fdot2(ua.hf, ub.hf, c, false);
}

// ---------------- K0: Wtt[ct][kgg][16][8] ----------------
__global__ __launch_bounds__(256) void k0_wt(const float* __restrict__ W,
                                             _Float16* __restrict__ Wtt) {
  for (int it = 0; it < 16; ++it) {
    int idx = blockIdx.x * 4096 + it * 256 + threadIdx.x;
    int e = idx & 7, ln = (idx >> 3) & 15, kgg = (idx >> 7) & 15,
        ct = idx >> 11;
    int c = ct * 16 + ln, k = kgg * 8 + e;
    Wtt[idx] = (_Float16)W[(size_t)(c >> 6) * 8192 + k * 64 + (c & 63)];
  }
}

// ---------------- K1: Wh = x @ W via MFMA f16 + fused s_i/s_j + exp tables --
__global__ __launch_bounds__(256) void k1_whm(
    const float* __restrict__ x, const _Float16* __restrict__ Wtt,
    const float* __restrict__ aw, const float* __restrict__ ab,
    _Float16* __restrict__ WhH, float* __restrict__ si2,
    _Float16* __restrict__ tjh, _Float16* __restrict__ djh,
    _Float16* __restrict__ e2jh, float* __restrict__ e2i_t,
    float* __restrict__ di_t) {
  __shared__ _Float16 xs[16][136];
  int tid = threadIdx.x;
#pragma unroll
  for (int t2 = 0; t2 < 2; ++t2) {
    int idx = t2 * 256 + tid;
    int row = idx >> 5, c4 = (idx & 31) * 4;
    float4 v = *(const float4*)(x + ((size_t)blockIdx.x * 16 + row) * FIN + c4);
    v4h hv;
    hv[0] = (_Float16)v.x; hv[1] = (_Float16)v.y;
    hv[2] = (_Float16)v.z; hv[3] = (_Float16)v.w;
    *(v4h*)(&xs[row][c4]) = hv;
  }
  __syncthreads();
  int w = tid >> 6, l = tid & 63;
  int kg = l >> 4, ln = l & 15;
  v4f acc[4] = {{}, {}, {}, {}};
#pragma unroll
  for (int ks = 0; ks < 4; ++ks) {
    v8h af = *(const v8h*)(&xs[ln][ks * 32 + kg * 8]);
    int kgg = ks * 4 + kg;
#pragma unroll
    for (int t = 0; t < 4; ++t) {
      int ct = w * 4 + t;
      v8h bf = *(const v8h*)(Wtt + (((size_t)ct * 16 + kgg) * 16 + ln) * 8);
      acc[t] = __builtin_amdgcn_mfma_f32_16x16x32_f16(af, bf, acc[t], 0, 0, 0);
    }
  }
  float a1v[4], a2v[4];
#pragma unroll
  for (int t = 0; t < 4; ++t) {
    a1v[t] = aw[w * 128 + t * 16 + ln];
    a2v[t] = aw[w * 128 + 64 + t * 16 + ln];
  }
  float abv = ab[w];
#pragma unroll
  for (int r = 0; r < 4; ++r) {
    float v1 = acc[0][r] * a1v[0] + acc[1][r] * a1v[1] +
               acc[2][r] * a1v[2] + acc[3][r] * a1v[3];
    float v2 = acc[0][r] * a2v[0] + acc[1][r] * a2v[1] +
               acc[2][r] * a2v[2] + acc[3][r] * a2v[3];
#pragma unroll
    for (int off = 1; off < 16; off <<= 1) {
      v1 += __shfl_xor(v1, off);
      v2 += __shfl_xor(v2, off);
    }
    if (ln == 0) {
      int gr = blockIdx.x * 16 + kg * 4 + r;
      int b_ = gr >> 10, n_ = gr & 1023;
      size_t row = ((size_t)b_ * HH + w) * NN + n_;
      float v1L = v1 * LOG2E;
      float tjL = (v2 + abv) * LOG2E;
      si2[row] = v1L;
      float e1i = __builtin_amdgcn_exp2f(v1L);
      float e2i = __builtin_amdgcn_exp2f(0.2f * v1L);
      e2i_t[row] = e2i;
      di_t[row] = e1i - e2i;
      float e1j = __builtin_amdgcn_exp2f(tjL);
      float e2j = __builtin_amdgcn_exp2f(0.2f * tjL);
      tjh[row] = (_Float16)tjL;
      e2jh[row] = (_Float16)e2j;
      djh[row] = (_Float16)(e1j - e2j);
    }
  }
#pragma unroll
  for (int t = 0; t < 4; ++t) {
#pragma unroll
    for (int r = 0; r < 4; ++r) {
      int gr = blockIdx.x * 16 + kg * 4 + r;
      int b_ = gr >> 10, n_ = gr & 1023;
      WhH[(((size_t)b_ * HH + w) * NN + n_) * 64 + (t * 16 + ln)] =
          (_Float16)acc[t][r];
    }
  }
}

// ------- KB: column sums via packed-f16 interp P + fdot2 + A bit-pack -------
__global__ __launch_bounds__(256) void kb_colsum_bits(
    const float* __restrict__ A, const float* __restrict__ si2,
    const float* __restrict__ e2i_t, const float* __restrict__ di_t,
    const _Float16* __restrict__ tjh, const _Float16* __restrict__ djh,
    const _Float16* __restrict__ e2jh, float* __restrict__ part,
    unsigned long long* __restrict__ Abits) {
  __shared__ v2h si_p[4][16], di_p[4][16], e2i_p[4][16];
  int b = blockIdx.z, is = blockIdx.y, jt = blockIdx.x;
  int tid = threadIdx.x;
  int w = tid >> 6, lane = tid & 63;
  int j = jt * 256 + tid;
  int i0 = is * 32;
  if (tid < 64) {
    int h = tid >> 4, pp = tid & 15;
    size_t row = ((size_t)(b * HH + h)) * NN + i0 + 2 * pp;
    si_p[h][pp] = cvt2(si2[row], si2[row + 1]);
    di_p[h][pp] = cvt2(di_t[row], di_t[row + 1]);
    e2i_p[h][pp] = cvt2(e2i_t[row], e2i_t[row + 1]);
  }
  __syncthreads();
  v2h tjb[4], djb[4], ejb[4];
#pragma unroll
  for (int h = 0; h < 4; ++h) {
    size_t jr = ((size_t)(b * HH + h)) * NN + j;
    _Float16 t = tjh[jr], d = djh[jr], e = e2jh[jr];
    tjb[h][0] = t; tjb[h][1] = t;
    djb[h][0] = d; djb[h][1] = d;
    ejb[h][0] = e; ejb[h][1] = e;
  }
  v2h big = {(_Float16)4096.0f, (_Float16)4096.0f};
  float acc[4] = {0.f, 0.f, 0.f, 0.f};
  const float* Ap = A + ((size_t)b * NN + i0) * NN + j;
  unsigned long long myword = 0ull;
#pragma unroll
  for (int c = 0; c < 4; ++c) {
    float av[8];
#pragma unroll
    for (int q = 0; q < 8; ++q) av[q] = Ap[(size_t)(c * 8 + q) * NN];
    v2h apk[4];
#pragma unroll
    for (int q = 0; q < 4; ++q) apk[q] = cvt2(av[2 * q], av[2 * q + 1]);
#pragma unroll
    for (int q = 0; q < 8; ++q) {
      unsigned long long m = __ballot(av[q] != 0.0f);
      if (lane == c * 8 + q) myword = m;
    }
#pragma unroll
    for (int h = 0; h < 4; ++h) {
      U8 si4, di4, ei4;
      si4.v = *(const v8h*)&si_p[h][c * 4];
      di4.v = *(const v8h*)&di_p[h][c * 4];
      ei4.v = *(const v8h*)&e2i_p[h][c * 4];
#pragma unroll
      for (int pp = 0; pp < 4; ++pp) {
        v2h f = si4.p[pp] + tjb[h];
        v2h s = clamp01(f * big);
        v2h ei = s * di4.p[pp] + ei4.p[pp];
        v2h ej = s * djb[h] + ejb[h];
        v2h p = ei * ej;
        acc[h] = dot2(p, apk[pp], acc[h]);
      }
    }
  }
  if (lane < 32)
    Abits[((size_t)b * NN + i0 + lane) * 16 + jt * 4 + w] = myword;
#pragma unroll
  for (int h = 0; h < 4; ++h)
    part[((size_t)(is * 32) + b * HH + h) * NN + j] = acc[h];
}

// ---------------- K3: r[j]=1/(colsum+eps); VTt = (f16) r*Wh, tiled ----------
__global__ __launch_bounds__(256) void k3_scale_tr(
    const _Float16* __restrict__ WhH, const float* __restrict__ part,
    _Float16* __restrict__ VTt) {
  __shared__ float rbuf[64];
  __shared__ _Float16 tile[64 * 66];
  int bid = blockIdx.x;
  int b = bid & 7, rest = bid >> 3;
  int h = rest & 3, jt = rest >> 2;
  int bh = b * HH + h, j0 = jt * 64;
  int tid = threadIdx.x;
  if (tid < 64) {
    float s = 0.f;
#pragma unroll
    for (int is = 0; is < 32; ++is)
      s += part[((size_t)(is * 32) + bh) * NN + j0 + tid];
    rbuf[tid] = 1.0f / (s + EPSV);
  }
  __syncthreads();
#pragma unroll
  for (int it = 0; it < 16; ++it) {
    int lin = it * 256 + tid;
    int jj = lin >> 6, o = lin & 63;
    float v = (float)WhH[((size_t)bh * NN + j0 + jj) * 64 + o] * rbuf[jj];
    tile[o * 66 + jj] = (_Float16)v;
  }
  __syncthreads();
#pragma unroll
  for (int it = 0; it < 16; ++it) {
    int lin = it * 256 + tid;
    int o = lin >> 6, jj64 = lin & 63;
    int j = j0 + jj64;
    int jb = j >> 5, jj = j & 31;
    VTt[(((size_t)bh * 32 + jb) * 64 + o) * 32 + jj] = tile[o * 66 + jj64];
  }
}

// ---------------- K4: out = P @ V' via MFMA, 64-row i-tiles -----------------
// grid 256: b=bid&7, hp=(bid>>3)&1, it=bid>>4 (16 tiles of 64 rows).
// 8 waves = (2 heads x 4 j-quarters); 4 i-fragments per wave -> each
// B-fragment feeds 4 MFMAs (VT L2 traffic halved vs 32-row version).
__global__ __launch_bounds__(512, 4) void k4_pv(
    const unsigned long long* __restrict__ Abits,
    const float* __restrict__ si2, const _Float16* __restrict__ tjh,
    const _Float16* __restrict__ djh, const _Float16* __restrict__ e2jh,
    const float* __restrict__ e2i_t, const float* __restrict__ di_t,
    const _Float16* __restrict__ VTt, float* __restrict__ out) {
  __shared__ unsigned long long Ab[64][17];
  __shared__ _Float16 tjl[2][1024];
  __shared__ _Float16 djl[2][1024];
  __shared__ _Float16 e2jl[2][1024];
  __shared__ _Float16 lut[256][8];
  __shared__ float sil[2][64], e2il[2][64], dil[2][64];
  __shared__ float red[2][2][64][33];
  int bid = blockIdx.x;
  int b = bid & 7, hp = (bid >> 3) & 1, it = bid >> 4;
  int i0 = it * 64;
  int tid = threadIdx.x;
  {
    size_t base = (size_t)(b * HH + hp * 2) * NN;
    const unsigned int* s1 = (const unsigned int*)(tjh + base);
    const unsigned int* s2 = (const unsigned int*)(djh + base);
    const unsigned int* s3 = (const unsigned int*)(e2jh + base);
    unsigned int* d1 = (unsigned int*)&tjl[0][0];
    unsigned int* d2 = (unsigned int*)&djl[0][0];
    unsigned int* d3 = (unsigned int*)&e2jl[0][0];
    d1[tid] = s1[tid]; d1[tid + 512] = s1[tid + 512];
    d2[tid] = s2[tid]; d2[tid + 512] = s2[tid + 512];
    d3[tid] = s3[tid]; d3[tid + 512] = s3[tid + 512];
  }
  if (tid < 128) {
    int hh = tid >> 6, ii = tid & 63;
    size_t row = (size_t)(b * HH + hp * 2 + hh) * NN + i0 + ii;
    sil[hh][ii] = si2[row];
    e2il[hh][ii] = e2i_t[row];
    dil[hh][ii] = di_t[row];
  }
  if (tid < 256) {
#pragma unroll
    for (int e = 0; e < 8; ++e)
      lut[tid][e] = ((tid >> e) & 1) ? (_Float16)1.0f : (_Float16)0.0f;
  }
  {
#pragma unroll
    for (int t2 = 0; t2 < 2; ++t2) {
      int idx = t2 * 512 + tid;
      int row = idx >> 4, word = idx & 15;
      Ab[row][word] = Abits[((size_t)b * NN + i0 + row) * 16 + word];
    }
  }
  __syncthreads();

  int w = tid >> 6, l = tid & 63;
  int hh = w & 1, jq4 = w >> 1;
  int kg = l >> 4, ln = l & 15;
  v2h si_f[4], e2_f[4], di_f[4];
#pragma unroll
  for (int f = 0; f < 4; ++f) {
    _Float16 s = (_Float16)sil[hh][f * 16 + ln];
    _Float16 e = (_Float16)e2il[hh][f * 16 + ln];
    _Float16 d = (_Float16)dil[hh][f * 16 + ln];
    si_f[f][0] = s; si_f[f][1] = s;
    e2_f[f][0] = e; e2_f[f][1] = e;
    di_f[f][0] = d; di_f[f][1] = d;
  }
  v2h big = {(_Float16)4096.0f, (_Float16)4096.0f};
  int bh = b * HH + hp * 2 + hh;
  v4f acc[4][4] = {};
  const _Float16* VTb = VTt + (size_t)bh * 32 * 64 * 32;
  int jbase = jq4 * 256;

  for (int jq = 0; jq < 8; ++jq) {
    int j = jbase + jq * 32 + kg * 8;
    int widx = j >> 6, sh = j & 63;
    U8 tj8, dj8, ej8;
    tj8.v = *(const v8h*)&tjl[hh][j];
    dj8.v = *(const v8h*)&djl[hh][j];
    ej8.v = *(const v8h*)&e2jl[hh][j];
    const _Float16* vb = VTb + (size_t)(j >> 5) * 2048 + kg * 8;
    v8h b0 = *(const v8h*)(vb + (0 * 16 + ln) * 32);
    v8h b1 = *(const v8h*)(vb + (1 * 16 + ln) * 32);
    v8h b2 = *(const v8h*)(vb + (2 * 16 + ln) * 32);
    v8h b3 = *(const v8h*)(vb + (3 * 16 + ln) * 32);
#pragma unroll
    for (int f = 0; f < 4; ++f) {
      unsigned int bits = (unsigned int)(Ab[f * 16 + ln][widx] >> sh) & 0xffu;
      U8 m, af;
      m.v = *(const v8h*)&lut[bits][0];
#pragma unroll
      for (int q = 0; q < 4; ++q) {
        v2h fv = tj8.p[q] + si_f[f];
        v2h s = clamp01(fv * big);
        v2h ej = s * dj8.p[q] + ej8.p[q];
        v2h ei = s * di_f[f] + e2_f[f];
        af.p[q] = ei * ej * m.p[q];
      }
      acc[f][0] =
          __builtin_amdgcn_mfma_f32_16x16x32_f16(af.v, b0, acc[f][0], 0, 0, 0);
      acc[f][1] =
          __builtin_amdgcn_mfma_f32_16x16x32_f16(af.v, b1, acc[f][1], 0, 0, 0);
      acc[f][2] =
          __builtin_amdgcn_mfma_f32_16x16x32_f16(af.v, b2, acc[f][2], 0, 0, 0);
      acc[f][3] =
          __builtin_amdgcn_mfma_f32_16x16x32_f16(af.v, b3, acc[f][3], 0, 0, 0);
    }
  }

  // 4-way j-quarter reduce, two passes (i-frag pairs) reusing red buffer.
#pragma unroll
  for (int pass = 0; pass < 2; ++pass) {
    int fA = pass * 2, fB = pass * 2 + 1;
    if (pass) __syncthreads();
    if (jq4 == 1 || jq4 == 3) {
      int slot = jq4 >> 1;
#pragma unroll
      for (int t = 0; t < 4; ++t)
#pragma unroll
        for (int r = 0; r < 4; ++r) {
          red[hh][slot][l][t * 4 + r] = acc[fA][t][r];
          red[hh][slot][l][16 + t * 4 + r] = acc[fB][t][r];
        }
    }
    __syncthreads();
    if (jq4 == 0 || jq4 == 2) {
      int slot = jq4 >> 1;
#pragma unroll
      for (int t = 0; t < 4; ++t)
#pragma unroll
        for (int r = 0; r < 4; ++r) {
          acc[fA][t][r] += red[hh][slot][l][t * 4 + r];
          acc[fB][t][r] += red[hh][slot][l][16 + t * 4 + r];
        }
    }
    __syncthreads();
    if (jq4 == 2) {
#pragma unroll
      for (int t = 0; t < 4; ++t)
#pragma unroll
        for (int r = 0; r < 4; ++r) {
          red[hh][0][l][t * 4 + r] = acc[fA][t][r];
          red[hh][0][l][16 + t * 4 + r] = acc[fB][t][r];
        }
    }
    __syncthreads();
    if (jq4 == 0) {
#pragma unroll
      for (int t = 0; t < 4; ++t)
#pragma unroll
        for (int r = 0; r < 4; ++r) {
          acc[fA][t][r] += red[hh][0][l][t * 4 + r];
          acc[fB][t][r] += red[hh][0][l][16 + t * 4 + r];
        }
#pragma unroll
      for (int r = 0; r < 4; ++r) {
        int giA = i0 + fA * 16 + kg * 4 + r;
        float* opA = out + ((size_t)b * NN + giA) * 256 + (hp * 2 + hh) * 64;
        opA[0 * 16 + ln] = acc[fA][0][r];
        opA[1 * 16 + ln] = acc[fA][1][r];
        opA[2 * 16 + ln] = acc[fA][2][r];
        opA[3 * 16 + ln] = acc[fA][3][r];
        float* opB = opA + 16 * 256;
        opB[0 * 16 + ln] = acc[fB][0][r];
        opB[1 * 16 + ln] = acc[fB][1][r];
        opB[2 * 16 + ln] = acc[fB][2][r];
        opB[3 * 16 + ln] = acc[fB][3][r];
      }
    }
  }
}

extern "C" void kernel_launch(void* const* d_in, const int* in_sizes, int n_in,
                              void* d_out, int out_size, void* d_ws,
                              size_t ws_size, hipStream_t stream) {
  const float* A = (const float*)d_in[0];
  const float* x = (const float*)d_in[1];
  const float* W = (const float*)d_in[2];
  const float* aw = (const float*)d_in[3];
  const float* ab = (const float*)d_in[4];
  float* out = (float*)d_out;
  char* ws = (char*)d_ws;
  _Float16* WhH = (_Float16*)ws;                        // 4 MB
  _Float16* VTt = (_Float16*)(ws + (4u << 20));         // 4 MB
  _Float16* Wtt = (_Float16*)(ws + (8u << 20));         // 64 KB
  float* si2 = (float*)(ws + (8u << 20) + (256u << 10));    // 128 KB
  float* part = (float*)(ws + (8u << 20) + (512u << 10));   // 4 MB
  unsigned long long* Abits =
      (unsigned long long*)(ws + (12u << 20) + (512u << 10));  // 1 MB
  char* tb = ws + (13u << 20) + (512u << 10);
  _Float16* tjh = (_Float16*)tb;                   // 64 KB (B,H,N) f16
  _Float16* djh = (_Float16*)(tb + (64u << 10));   // 64 KB
  _Float16* e2jh = (_Float16*)(tb + (128u << 10)); // 64 KB
  float* e2i_t = (float*)(tb + (192u << 10));      // 128 KB
  float* di_t = (float*)(tb + (320u << 10));       // 128 KB

  hipLaunchKernelGGL(k0_wt, dim3(8), dim3(256), 0, stream, W, Wtt);
  hipLaunchKernelGGL(k1_whm, dim3(512), dim3(256), 0, stream, x, Wtt, aw, ab,
                     WhH, si2, tjh, djh, e2jh, e2i_t, di_t);
  hipLaunchKernelGGL(kb_colsum_bits, dim3(4, 32, BB), dim3(256), 0, stream, A,
                     si2, e2i_t, di_t, tjh, djh, e2jh, part, Abits);
  hipLaunchKernelGGL(k3_scale_tr, dim3(512), dim3(256), 0, stream, WhH, part,
                     VTt);
  hipLaunchKernelGGL(k4_pv, dim3(256), dim3(512), 0, stream, Abits, si2, tjh,
                     djh, e2jh, e2i_t, di_t, VTt, out);
}

// Round 18
// 41.033 us; speedup vs baseline: 4.2408x; 1.0900x over previous
//
#include <hip/hip_runtime.h>
#include <hip/hip_bf16.h>
#include <hip/hip_fp16.h>

#define BB 8
#define NN 1024
#define FIN 128
#define FOUT 64
#define HH 4
#define EPSV 1e-7f
#define SLOPE 0.2f
#define LOG2E 1.44269504088896340736f

typedef _Float16 v8h __attribute__((ext_vector_type(8)));
typedef _Float16 v4h __attribute__((ext_vector_type(4)));
typedef _Float16 v2h __attribute__((ext_vector_type(2)));
typedef __fp16 v2hf __attribute__((ext_vector_type(2)));
typedef float v4f __attribute__((ext_vector_type(4)));

union U8 { v2h p[4]; v8h v; };
union U2 { v2hf hf; v2h h; };

__device__ __forceinline__ v2h clamp01(v2h x) {
  v2h zero = {(_Float16)0.0f, (_Float16)0.0f};
  v2h one = {(_Float16)1.0f, (_Float16)1.0f};
  return __builtin_elementwise_min(__builtin_elementwise_max(x, zero), one);
}

__device__ __forceinline__ v2h cvt2(float a, float b) {
  U2 u;
  u.hf = __builtin_amdgcn_cvt_pkrtz(a, b);
  return u.h;
}

__device__ __forceinline__ float dot2(v2h a, v2h b, float c) {
  U2 ua, ub;
  ua.h = a;
  ub.h = b;
  return __builtin_amdgcn_fdot2(ua.hf, ub.hf, c, false);
}

// ---------------- K0: Wtt[ct][kgg][16][8] ----------------
__global__ __launch_bounds__(256) void k0_wt(const float* __restrict__ W,
                                             _Float16* __restrict__ Wtt) {
  for (int it = 0; it < 16; ++it) {
    int idx = blockIdx.x * 4096 + it * 256 + threadIdx.x;
    int e = idx & 7, ln = (idx >> 3) & 15, kgg = (idx >> 7) & 15,
        ct = idx >> 11;
    int c = ct * 16 + ln, k = kgg * 8 + e;
    Wtt[idx] = (_Float16)W[(size_t)(c >> 6) * 8192 + k * 64 + (c & 63)];
  }
}

// ---- K1: Wh = x@W MFMA; s_i/s_j + exp tables; Wh stored TILED (unscaled);
//      also zeroes colsum (for kb's atomics). grid 512, block 256. ----------
__global__ __launch_bounds__(256) void k1_whm(
    const float* __restrict__ x, const _Float16* __restrict__ Wtt,
    const float* __restrict__ aw, const float* __restrict__ ab,
    _Float16* __restrict__ WhTt, float* __restrict__ si2,
    _Float16* __restrict__ tjh, _Float16* __restrict__ djh,
    _Float16* __restrict__ e2jh, float* __restrict__ e2i_t,
    float* __restrict__ di_t, float* __restrict__ colsum) {
  __shared__ _Float16 xs[16][136];
  int tid = threadIdx.x;
  int bid = blockIdx.x;
  if (tid < 64) colsum[bid * 64 + tid] = 0.0f;  // 512*64 = 32768 = B*H*N
#pragma unroll
  for (int t2 = 0; t2 < 2; ++t2) {
    int idx = t2 * 256 + tid;
    int row = idx >> 5, c4 = (idx & 31) * 4;
    float4 v = *(const float4*)(x + ((size_t)bid * 16 + row) * FIN + c4);
    v4h hv;
    hv[0] = (_Float16)v.x; hv[1] = (_Float16)v.y;
    hv[2] = (_Float16)v.z; hv[3] = (_Float16)v.w;
    *(v4h*)(&xs[row][c4]) = hv;
  }
  __syncthreads();
  int w = tid >> 6, l = tid & 63;
  int kg = l >> 4, ln = l & 15;
  v4f acc[4] = {{}, {}, {}, {}};
#pragma unroll
  for (int ks = 0; ks < 4; ++ks) {
    v8h af = *(const v8h*)(&xs[ln][ks * 32 + kg * 8]);
    int kgg = ks * 4 + kg;
#pragma unroll
    for (int t = 0; t < 4; ++t) {
      int ct = w * 4 + t;
      v8h bf = *(const v8h*)(Wtt + (((size_t)ct * 16 + kgg) * 16 + ln) * 8);
      acc[t] = __builtin_amdgcn_mfma_f32_16x16x32_f16(af, bf, acc[t], 0, 0, 0);
    }
  }
  float a1v[4], a2v[4];
#pragma unroll
  for (int t = 0; t < 4; ++t) {
    a1v[t] = aw[w * 128 + t * 16 + ln];
    a2v[t] = aw[w * 128 + 64 + t * 16 + ln];
  }
  float abv = ab[w];
#pragma unroll
  for (int r = 0; r < 4; ++r) {
    float v1 = acc[0][r] * a1v[0] + acc[1][r] * a1v[1] +
               acc[2][r] * a1v[2] + acc[3][r] * a1v[3];
    float v2 = acc[0][r] * a2v[0] + acc[1][r] * a2v[1] +
               acc[2][r] * a2v[2] + acc[3][r] * a2v[3];
#pragma unroll
    for (int off = 1; off < 16; off <<= 1) {
      v1 += __shfl_xor(v1, off);
      v2 += __shfl_xor(v2, off);
    }
    if (ln == 0) {
      int gr = bid * 16 + kg * 4 + r;
      int b_ = gr >> 10, n_ = gr & 1023;
      size_t row = ((size_t)b_ * HH + w) * NN + n_;
      float v1L = v1 * LOG2E;
      float tjL = (v2 + abv) * LOG2E;
      si2[row] = v1L;
      float e1i = __builtin_amdgcn_exp2f(v1L);
      float e2i = __builtin_amdgcn_exp2f(0.2f * v1L);
      e2i_t[row] = e2i;
      di_t[row] = e1i - e2i;
      float e1j = __builtin_amdgcn_exp2f(tjL);
      float e2j = __builtin_amdgcn_exp2f(0.2f * tjL);
      tjh[row] = (_Float16)tjL;
      e2jh[row] = (_Float16)e2j;
      djh[row] = (_Float16)(e1j - e2j);
    }
  }
  // tiled store: WhTt[((bh*32 + jb)*64 + o)*32 + jj], o = t*16+ln,
  // jb = (bid&63)>>1, jj = (bid&1)*16 + kg*4 + r (4 consecutive -> v4h)
  {
    int b_ = bid >> 6;
    int bh = b_ * HH + w;
    int jb = (bid & 63) >> 1;
    int jj0 = (bid & 1) * 16 + kg * 4;
#pragma unroll
    for (int t = 0; t < 4; ++t) {
      v4h hv;
#pragma unroll
      for (int r = 0; r < 4; ++r) hv[r] = (_Float16)acc[t][r];
      *(v4h*)(WhTt + (((size_t)bh * 32 + jb) * 64 + (t * 16 + ln)) * 32 +
              jj0) = hv;
    }
  }
}

// ------- KB: column sums via packed-f16 interp P + fdot2 + A bit-pack;
//         sums accumulated into colsum via atomicAdd (k3 eliminated). -------
__global__ __launch_bounds__(256) void kb_colsum_bits(
    const float* __restrict__ A, const float* __restrict__ si2,
    const float* __restrict__ e2i_t, const float* __restrict__ di_t,
    const _Float16* __restrict__ tjh, const _Float16* __restrict__ djh,
    const _Float16* __restrict__ e2jh, float* __restrict__ colsum,
    unsigned long long* __restrict__ Abits) {
  __shared__ v2h si_p[4][16], di_p[4][16], e2i_p[4][16];
  int b = blockIdx.z, is = blockIdx.y, jt = blockIdx.x;
  int tid = threadIdx.x;
  int w = tid >> 6, lane = tid & 63;
  int j = jt * 256 + tid;
  int i0 = is * 32;
  if (tid < 64) {
    int h = tid >> 4, pp = tid & 15;
    size_t row = ((size_t)(b * HH + h)) * NN + i0 + 2 * pp;
    si_p[h][pp] = cvt2(si2[row], si2[row + 1]);
    di_p[h][pp] = cvt2(di_t[row], di_t[row + 1]);
    e2i_p[h][pp] = cvt2(e2i_t[row], e2i_t[row + 1]);
  }
  __syncthreads();
  v2h tjb[4], djb[4], ejb[4];
#pragma unroll
  for (int h = 0; h < 4; ++h) {
    size_t jr = ((size_t)(b * HH + h)) * NN + j;
    _Float16 t = tjh[jr], d = djh[jr], e = e2jh[jr];
    tjb[h][0] = t; tjb[h][1] = t;
    djb[h][0] = d; djb[h][1] = d;
    ejb[h][0] = e; ejb[h][1] = e;
  }
  v2h big = {(_Float16)4096.0f, (_Float16)4096.0f};
  float acc[4] = {0.f, 0.f, 0.f, 0.f};
  const float* Ap = A + ((size_t)b * NN + i0) * NN + j;
  unsigned long long myword = 0ull;
#pragma unroll
  for (int c = 0; c < 4; ++c) {
    float av[8];
#pragma unroll
    for (int q = 0; q < 8; ++q) av[q] = Ap[(size_t)(c * 8 + q) * NN];
    v2h apk[4];
#pragma unroll
    for (int q = 0; q < 4; ++q) apk[q] = cvt2(av[2 * q], av[2 * q + 1]);
#pragma unroll
    for (int q = 0; q < 8; ++q) {
      unsigned long long m = __ballot(av[q] != 0.0f);
      if (lane == c * 8 + q) myword = m;
    }
#pragma unroll
    for (int h = 0; h < 4; ++h) {
      U8 si4, di4, ei4;
      si4.v = *(const v8h*)&si_p[h][c * 4];
      di4.v = *(const v8h*)&di_p[h][c * 4];
      ei4.v = *(const v8h*)&e2i_p[h][c * 4];
#pragma unroll
      for (int pp = 0; pp < 4; ++pp) {
        v2h f = si4.p[pp] + tjb[h];
        v2h s = clamp01(f * big);
        v2h ei = s * di4.p[pp] + ei4.p[pp];
        v2h ej = s * djb[h] + ejb[h];
        v2h p = ei * ej;
        acc[h] = dot2(p, apk[pp], acc[h]);
      }
    }
  }
  if (lane < 32)
    Abits[((size_t)b * NN + i0 + lane) * 16 + jt * 4 + w] = myword;
#pragma unroll
  for (int h = 0; h < 4; ++h)
    atomicAdd(&colsum[((size_t)(b * HH + h)) * NN + j], acc[h]);
}

// ---------------- K4: out = P' @ Wh via MFMA, 64-row i-tiles ----------------
// r[j] = 1/(colsum+eps) folded into dj/e2j tables AT STAGING (hot loop
// unchanged); V' = unscaled tiled Wh. grid 256, block 512.
__global__ __launch_bounds__(512, 4) void k4_pv(
    const unsigned long long* __restrict__ Abits,
    const float* __restrict__ si2, const _Float16* __restrict__ tjh,
    const _Float16* __restrict__ djh, const _Float16* __restrict__ e2jh,
    const float* __restrict__ e2i_t, const float* __restrict__ di_t,
    const _Float16* __restrict__ WhTt, const float* __restrict__ colsum,
    float* __restrict__ out) {
  __shared__ unsigned long long Ab[64][17];
  __shared__ _Float16 tjl[2][1024];
  __shared__ _Float16 djl[2][1024];
  __shared__ _Float16 e2jl[2][1024];
  __shared__ _Float16 lut[256][8];
  __shared__ float sil[2][64], e2il[2][64], dil[2][64];
  __shared__ float red[2][2][64][33];
  int bid = blockIdx.x;
  int b = bid & 7, hp = (bid >> 3) & 1, it = bid >> 4;
  int i0 = it * 64;
  int tid = threadIdx.x;
  // stage j-tables with r[j] folded into dj/e2j
  {
    size_t base = (size_t)(b * HH + hp * 2) * NN;
#pragma unroll
    for (int t2 = 0; t2 < 4; ++t2) {
      int idx = t2 * 512 + tid;
      int hh = idx >> 10, j = idx & 1023;
      size_t row = base + (size_t)hh * NN + j;
      float rr = 1.0f / (colsum[row] + EPSV);
      tjl[hh][j] = tjh[row];
      djl[hh][j] = (_Float16)((float)djh[row] * rr);
      e2jl[hh][j] = (_Float16)((float)e2jh[row] * rr);
    }
  }
  if (tid < 128) {
    int hh = tid >> 6, ii = tid & 63;
    size_t row = (size_t)(b * HH + hp * 2 + hh) * NN + i0 + ii;
    sil[hh][ii] = si2[row];
    e2il[hh][ii] = e2i_t[row];
    dil[hh][ii] = di_t[row];
  }
  if (tid < 256) {
#pragma unroll
    for (int e = 0; e < 8; ++e)
      lut[tid][e] = ((tid >> e) & 1) ? (_Float16)1.0f : (_Float16)0.0f;
  }
  {
#pragma unroll
    for (int t2 = 0; t2 < 2; ++t2) {
      int idx = t2 * 512 + tid;
      int row = idx >> 4, word = idx & 15;
      Ab[row][word] = Abits[((size_t)b * NN + i0 + row) * 16 + word];
    }
  }
  __syncthreads();

  int w = tid >> 6, l = tid & 63;
  int hh = w & 1, jq4 = w >> 1;
  int kg = l >> 4, ln = l & 15;
  v2h si_f[4], e2_f[4], di_f[4];
#pragma unroll
  for (int f = 0; f < 4; ++f) {
    _Float16 s = (_Float16)sil[hh][f * 16 + ln];
    _Float16 e = (_Float16)e2il[hh][f * 16 + ln];
    _Float16 d = (_Float16)dil[hh][f * 16 + ln];
    si_f[f][0] = s; si_f[f][1] = s;
    e2_f[f][0] = e; e2_f[f][1] = e;
    di_f[f][0] = d; di_f[f][1] = d;
  }
  v2h big = {(_Float16)4096.0f, (_Float16)4096.0f};
  int bh = b * HH + hp * 2 + hh;
  v4f acc[4][4] = {};
  const _Float16* VTb = WhTt + (size_t)bh * 32 * 64 * 32;
  int jbase = jq4 * 256;

  for (int jq = 0; jq < 8; ++jq) {
    int j = jbase + jq * 32 + kg * 8;
    int widx = j >> 6, sh = j & 63;
    U8 tj8, dj8, ej8;
    tj8.v = *(const v8h*)&tjl[hh][j];
    dj8.v = *(const v8h*)&djl[hh][j];
    ej8.v = *(const v8h*)&e2jl[hh][j];
    const _Float16* vb = VTb + (size_t)(j >> 5) * 2048 + kg * 8;
    v8h b0 = *(const v8h*)(vb + (0 * 16 + ln) * 32);
    v8h b1 = *(const v8h*)(vb + (1 * 16 + ln) * 32);
    v8h b2 = *(const v8h*)(vb + (2 * 16 + ln) * 32);
    v8h b3 = *(const v8h*)(vb + (3 * 16 + ln) * 32);
#pragma unroll
    for (int f = 0; f < 4; ++f) {
      unsigned int bits = (unsigned int)(Ab[f * 16 + ln][widx] >> sh) & 0xffu;
      U8 m, af;
      m.v = *(const v8h*)&lut[bits][0];
#pragma unroll
      for (int q = 0; q < 4; ++q) {
        v2h fv = tj8.p[q] + si_f[f];
        v2h s = clamp01(fv * big);
        v2h ej = s * dj8.p[q] + ej8.p[q];
        v2h ei = s * di_f[f] + e2_f[f];
        af.p[q] = ei * ej * m.p[q];
      }
      acc[f][0] =
          __builtin_amdgcn_mfma_f32_16x16x32_f16(af.v, b0, acc[f][0], 0, 0, 0);
      acc[f][1] =
          __builtin_amdgcn_mfma_f32_16x16x32_f16(af.v, b1, acc[f][1], 0, 0, 0);
      acc[f][2] =
          __builtin_amdgcn_mfma_f32_16x16x32_f16(af.v, b2, acc[f][2], 0, 0, 0);
      acc[f][3] =
          __builtin_amdgcn_mfma_f32_16x16x32_f16(af.v, b3, acc[f][3], 0, 0, 0);
    }
  }

#pragma unroll
  for (int pass = 0; pass < 2; ++pass) {
    int fA = pass * 2, fB = pass * 2 + 1;
    if (pass) __syncthreads();
    if (jq4 == 1 || jq4 == 3) {
      int slot = jq4 >> 1;
#pragma unroll
      for (int t = 0; t < 4; ++t)
#pragma unroll
        for (int r = 0; r < 4; ++r) {
          red[hh][slot][l][t * 4 + r] = acc[fA][t][r];
          red[hh][slot][l][16 + t * 4 + r] = acc[fB][t][r];
        }
    }
    __syncthreads();
    if (jq4 == 0 || jq4 == 2) {
      int slot = jq4 >> 1;
#pragma unroll
      for (int t = 0; t < 4; ++t)
#pragma unroll
        for (int r = 0; r < 4; ++r) {
          acc[fA][t][r] += red[hh][slot][l][t * 4 + r];
          acc[fB][t][r] += red[hh][slot][l][16 + t * 4 + r];
        }
    }
    __syncthreads();
    if (jq4 == 2) {
#pragma unroll
      for (int t = 0; t < 4; ++t)
#pragma unroll
        for (int r = 0; r < 4; ++r) {
          red[hh][0][l][t * 4 + r] = acc[fA][t][r];
          red[hh][0][l][16 + t * 4 + r] = acc[fB][t][r];
        }
    }
    __syncthreads();
    if (jq4 == 0) {
#pragma unroll
      for (int t = 0; t < 4; ++t)
#pragma unroll
        for (int r = 0; r < 4; ++r) {
          acc[fA][t][r] += red[hh][0][l][t * 4 + r];
          acc[fB][t][r] += red[hh][0][l][16 + t * 4 + r];
        }
#pragma unroll
      for (int r = 0; r < 4; ++r) {
        int giA = i0 + fA * 16 + kg * 4 + r;
        float* opA = out + ((size_t)b * NN + giA) * 256 + (hp * 2 + hh) * 64;
        opA[0 * 16 + ln] = acc[fA][0][r];
        opA[1 * 16 + ln] = acc[fA][1][r];
        opA[2 * 16 + ln] = acc[fA][2][r];
        opA[3 * 16 + ln] = acc[fA][3][r];
        float* opB = opA + 16 * 256;
        opB[0 * 16 + ln] = acc[fB][0][r];
        opB[1 * 16 + ln] = acc[fB][1][r];
        opB[2 * 16 + ln] = acc[fB][2][r];
        opB[3 * 16 + ln] = acc[fB][3][r];
      }
    }
  }
}

extern "C" void kernel_launch(void* const* d_in, const int* in_sizes, int n_in,
                              void* d_out, int out_size, void* d_ws,
                              size_t ws_size, hipStream_t stream) {
  const float* A = (const float*)d_in[0];
  const float* x = (const float*)d_in[1];
  const float* W = (const float*)d_in[2];
  const float* aw = (const float*)d_in[3];
  const float* ab = (const float*)d_in[4];
  float* out = (float*)d_out;
  char* ws = (char*)d_ws;
  _Float16* WhTt = (_Float16*)ws;                       // 4 MB tiled Wh
  _Float16* Wtt = (_Float16*)(ws + (4u << 20));         // 64 KB
  float* si2 = (float*)(ws + (4u << 20) + (64u << 10));     // 128 KB
  float* colsum = (float*)(ws + (4u << 20) + (192u << 10)); // 128 KB
  unsigned long long* Abits =
      (unsigned long long*)(ws + (4u << 20) + (320u << 10));  // 1 MB
  char* tb = ws + (5u << 20) + (320u << 10);
  _Float16* tjh = (_Float16*)tb;                   // 64 KB (B,H,N) f16
  _Float16* djh = (_Float16*)(tb + (64u << 10));   // 64 KB
  _Float16* e2jh = (_Float16*)(tb + (128u << 10)); // 64 KB
  float* e2i_t = (float*)(tb + (192u << 10));      // 128 KB
  float* di_t = (float*)(tb + (320u << 10));       // 128 KB

  hipLaunchKernelGGL(k0_wt, dim3(8), dim3(256), 0, stream, W, Wtt);
  hipLaunchKernelGGL(k1_whm, dim3(512), dim3(256), 0, stream, x, Wtt, aw, ab,
                     WhTt, si2, tjh, djh, e2jh, e2i_t, di_t, colsum);
  hipLaunchKernelGGL(kb_colsum_bits, dim3(4, 32, BB), dim3(256), 0, stream, A,
                     si2, e2i_t, di_t, tjh, djh, e2jh, colsum, Abits);
  hipLaunchKernelGGL(k4_pv, dim3(256), dim3(512), 0, stream, Abits, si2, tjh,
                     djh, e2jh, e2i_t, di_t, WhTt, colsum, out);
}